// Round 10
// baseline (63.079 us; speedup 1.0000x reference)
//
#include <hip/hip_runtime.h>
#include <hip/hip_bf16.h>
#include <climits>

typedef __bf16 bf16;
typedef __bf16 bf16x4 __attribute__((ext_vector_type(4)));
typedef __bf16 bf16x8 __attribute__((ext_vector_type(8)));
typedef float f32x4 __attribute__((ext_vector_type(4)));

#define NB 8
#define L_ 4096
#define C_ 512
#define KW 5
#define NS 8

#define GLOAD_LDS16(g, l)                                                      \
  __builtin_amdgcn_global_load_lds(                                            \
      (const __attribute__((address_space(1))) void*)(g),                      \
      (__attribute__((address_space(3))) void*)(l), 16, 0, 0)

// ---------------------------------------------------------------------------
// bias2[n] = b_pw[n] + sum_c b_dw[c]*w_pw[n][c]   (fp32-exact)
// ---------------------------------------------------------------------------
__global__ __launch_bounds__(256) void bias_kernel(
    const float* __restrict__ w_pw, const float* __restrict__ b_dw,
    const float* __restrict__ b_pw, float* __restrict__ bias2) {
  const int n = blockIdx.x;
  const int t = threadIdx.x;
  float2 v = *(const float2*)(w_pw + n * C_ + 2 * t);
  float2 bb = *(const float2*)(b_dw + 2 * t);
  float s = v.x * bb.x + v.y * bb.y;
#pragma unroll
  for (int off = 32; off; off >>= 1) s += __shfl_down(s, off, 64);
  __shared__ float part[4];
  if ((t & 63) == 0) part[t >> 6] = s;
  __syncthreads();
  if (t == 0) bias2[n] = b_pw[n] + part[0] + part[1] + part[2] + part[3];
}

// ---------------------------------------------------------------------------
// packB: w_pw fp32 -> bf16, MFMA B-frag order for 16-wave x 2-frag layout.
// gid = ((kk*16 + wv)*2 + nf)*64 + lane:
//   col n = wv*32 + nf*16 + (lane&15), ch c = kk*32 + (lane>>4)*8 .. +8
// ---------------------------------------------------------------------------
__global__ __launch_bounds__(256) void packB_kernel(
    const float* __restrict__ w_pw, bf16* __restrict__ pkB) {
  const int gid = blockIdx.x * 256 + threadIdx.x;  // 0..32767
  const int lane = gid & 63;
  const int nf = (gid >> 6) & 1;
  const int wv = (gid >> 7) & 15;
  const int kk = gid >> 11;
  const int n = wv * 32 + nf * 16 + (lane & 15);
  const int c = kk * 32 + (lane >> 4) * 8;
  const float* s = w_pw + n * C_ + c;
  float4 a = *(const float4*)s;
  float4 b4 = *(const float4*)(s + 4);
  bf16x8 h;
  h[0] = (bf16)a.x; h[1] = (bf16)a.y; h[2] = (bf16)a.z; h[3] = (bf16)a.w;
  h[4] = (bf16)b4.x; h[5] = (bf16)b4.y; h[6] = (bf16)b4.z; h[7] = (bf16)b4.w;
  *(bf16x8*)(pkB + (size_t)gid * 8) = h;
}

// ---------------------------------------------------------------------------
// conv: rolling-window segment-causal depthwise conv, register streaming,
// no LDS, no barriers. Thread owns (batch, channel-quad, 32 rows).
// Output dwp: bf16, packed in MFMA A-fragment order:
//   elem (b,l,c) -> (b*256 + l/16)*8192 + (c/32)*512
//                   + ((l&15) + ((c>>3)&3)*16)*8 + (c&7)
// so a GEMM wave's A-frag (16 rows x 32 ch) is 64 lanes x 16B contiguous.
// ---------------------------------------------------------------------------
__global__ __launch_bounds__(256) void conv_kernel(
    const float* __restrict__ x, const int* __restrict__ segb,
    const float* __restrict__ w_dw, bf16* __restrict__ dwp) {
  const int g = blockIdx.x * 256 + threadIdx.x;
  const int q = g & 127;         // channel quad (4 ch)
  const int rest = g >> 7;       // 0..1023
  const int b = rest >> 7;       // 0..7
  const int chunk = rest & 127;  // 0..127
  const int l0 = chunk << 5;     // 32 rows per thread

  // taps: wt[m][i] = w_dw[q*4+i][m]
  float4 raw[5];
#pragma unroll
  for (int i = 0; i < 5; ++i)
    raw[i] = *(const float4*)(w_dw + q * 20 + i * 4);
  f32x4 wt[5];
#pragma unroll
  for (int m = 0; m < 5; ++m)
#pragma unroll
    for (int i = 0; i < 4; ++i) {
      const int f = i * 5 + m;
      wt[m][i] = ((const float*)&raw[f >> 2])[f & 3];
    }

  const int* sb = segb + b * NS * 2;
  int stv[NS];
#pragma unroll
  for (int s = 0; s < NS; ++s) stv[s] = sb[2 * s];
  auto nxt = [&](int l) {
    int nn = INT_MAX;
#pragma unroll
    for (int s = 0; s < NS; ++s)
      nn = (stv[s] > l && stv[s] < nn) ? stv[s] : nn;
    return nn;
  };
  int ns = nxt(l0 - 4);

  const float* xbase = x + ((size_t)(b * L_ + l0)) * C_ + q * 4;
  // packed-store constant part
  bf16* dbase = dwp + (size_t)b * 2097152 + (q >> 3) * 512 +
                ((q >> 1) & 3) * 128 + (q & 1) * 4;

  const f32x4 z4 = (f32x4){0.f, 0.f, 0.f, 0.f};
  f32x4 w0 = z4, w1 = z4, w2 = z4, w3 = z4;

#pragma unroll
  for (int i = 0; i < 4; ++i) {
    const int l = l0 - 4 + i;
    f32x4 nv = z4;
    if (l >= 0) nv = *(const f32x4*)(xbase + (ptrdiff_t)(i - 4) * C_);
    if (l == ns) { w0 = z4; w1 = z4; w2 = z4; w3 = z4; ns = nxt(l); }
    w0 = w1; w1 = w2; w2 = w3; w3 = nv;
  }

  auto dorow = [&](int l, f32x4& A, f32x4& B4, f32x4& Cc, f32x4& D,
                   const f32x4& E) {
    if (l == ns) { A = z4; B4 = z4; Cc = z4; D = z4; ns = nxt(l); }
    f32x4 r;
#pragma unroll
    for (int i = 0; i < 4; ++i) {
      float a = A[i] * wt[0][i];
      a = fmaf(B4[i], wt[1][i], a);
      a = fmaf(Cc[i], wt[2][i], a);
      a = fmaf(D[i], wt[3][i], a);
      a = fmaf(E[i], wt[4][i], a);
      r[i] = a;
    }
    bf16x4 h;
#pragma unroll
    for (int i = 0; i < 4; ++i) h[i] = (bf16)r[i];
    *(bf16x4*)(dbase + (l >> 4) * 8192 + (l & 15) * 8) = h;
  };

#pragma unroll 1
  for (int g8 = 0; g8 < 8; ++g8) {
    const int lb = l0 + g8 * 4;
    f32x4 n0 = *(const f32x4*)(xbase + (ptrdiff_t)(g8 * 4 + 0) * C_);
    f32x4 n1 = *(const f32x4*)(xbase + (ptrdiff_t)(g8 * 4 + 1) * C_);
    f32x4 n2 = *(const f32x4*)(xbase + (ptrdiff_t)(g8 * 4 + 2) * C_);
    f32x4 n3 = *(const f32x4*)(xbase + (ptrdiff_t)(g8 * 4 + 3) * C_);
    dorow(lb + 0, w0, w1, w2, w3, n0);
    dorow(lb + 1, w1, w2, w3, n0, n1);
    dorow(lb + 2, w2, w3, n0, n1, n2);
    dorow(lb + 3, w3, n0, n1, n2, n3);
    w0 = n0; w1 = n1; w2 = n2; w3 = n3;
  }
}

// ---------------------------------------------------------------------------
// gemm: out[b,l,n] = dwp[b,l,:] . w_pw[n,:] + bias2[n].
// 512 blocks x 1024 thr (16 waves). Per block: one 64KB linear DMA of the
// packed A-tile into LDS + ONE barrier, then a barrier-free K-loop:
// wave wv owns cols wv*32..+32 (acc[4][2]); A-frags from LDS, B-frags
// L2->VGPR from packed pkB; both software-prefetched one step (ping-pong).
// ---------------------------------------------------------------------------
__global__ __launch_bounds__(1024) void gemm_kernel(
    const bf16* __restrict__ dwp, const bf16* __restrict__ pkB,
    const float* __restrict__ bias2, float* __restrict__ out) {
  __shared__ __align__(16) bf16 As[32768];  // 64 KB packed A-tile

  const int t = threadIdx.x;
  const int lane = t & 63;
  const int wv = t >> 6;  // 0..15
  const int b = blockIdx.x >> 6;
  const int mt = blockIdx.x & 63;  // 64-row tile within batch row
  const int l0 = mt << 6;

  // ---- A fill: 64KB linear DMA, 4 rounds x 16KB
  const bf16* asrc = dwp + ((size_t)b * 256 + mt * 4) * 8192;
#pragma unroll
  for (int i = 0; i < 4; ++i)
    GLOAD_LDS16(asrc + (i * 1024 + t) * 8, As + (i * 1024 + (t & ~63)) * 8);

  // ---- B-frag base (packed): nf stride 512, kk stride 16384 elems
  const bf16* pb = pkB + ((size_t)wv * 2 * 64 + lane) * 8;

  bf16x8 bbA[2], bbB[2], afA[4], afB[4];
#pragma unroll
  for (int nf = 0; nf < 2; ++nf)
    bbA[nf] = *(const bf16x8*)(pb + nf * 512);  // bb(0), independent of LDS

  __syncthreads();  // A-tile resident (drains DMA); the ONLY barrier

  const int aL = lane * 8;  // A-frag lane offset within a 1KB frag
#pragma unroll
  for (int mf = 0; mf < 4; ++mf)
    afA[mf] = *(const bf16x8*)&As[mf * 16 * 64 * 8 + aL];  // af(0)

  f32x4 acc[4][2];
#pragma unroll
  for (int i = 0; i < 4; ++i)
#pragma unroll
    for (int j = 0; j < 2; ++j) acc[i][j] = (f32x4){0.f, 0.f, 0.f, 0.f};

#pragma unroll 1
  for (int k2 = 0; k2 < 16; k2 += 2) {
    // step k2 (A-set): prefetch k2+1 into B-set, then MFMA on A-set
#pragma unroll
    for (int nf = 0; nf < 2; ++nf)
      bbB[nf] = *(const bf16x8*)(pb + (k2 + 1) * 16384 + nf * 512);
#pragma unroll
    for (int mf = 0; mf < 4; ++mf)
      afB[mf] = *(const bf16x8*)&As[(mf * 16 + (k2 + 1)) * 512 + aL];
    __builtin_amdgcn_s_setprio(1);
#pragma unroll
    for (int nf = 0; nf < 2; ++nf)
#pragma unroll
      for (int mf = 0; mf < 4; ++mf)
        acc[mf][nf] = __builtin_amdgcn_mfma_f32_16x16x32_bf16(
            afA[mf], bbA[nf], acc[mf][nf], 0, 0, 0);
    __builtin_amdgcn_s_setprio(0);

    // step k2+1 (B-set): prefetch k2+2 into A-set, then MFMA on B-set
    if (k2 + 2 < 16) {
#pragma unroll
      for (int nf = 0; nf < 2; ++nf)
        bbA[nf] = *(const bf16x8*)(pb + (k2 + 2) * 16384 + nf * 512);
#pragma unroll
      for (int mf = 0; mf < 4; ++mf)
        afA[mf] = *(const bf16x8*)&As[(mf * 16 + (k2 + 2)) * 512 + aL];
    }
    __builtin_amdgcn_s_setprio(1);
#pragma unroll
    for (int nf = 0; nf < 2; ++nf)
#pragma unroll
      for (int mf = 0; mf < 4; ++mf)
        acc[mf][nf] = __builtin_amdgcn_mfma_f32_16x16x32_bf16(
            afB[mf], bbB[nf], acc[mf][nf], 0, 0, 0);
    __builtin_amdgcn_s_setprio(0);
  }

  // ---- epilogue: fp32 + bias2
  const int col0 = wv * 32 + (lane & 15);
  const int cg = lane >> 4;
  float bia[2];
#pragma unroll
  for (int nf = 0; nf < 2; ++nf) bia[nf] = bias2[col0 + nf * 16];
  const int rb0 = l0 + (cg << 2);
#pragma unroll
  for (int mf = 0; mf < 4; ++mf) {
#pragma unroll
    for (int i = 0; i < 4; ++i) {
      const int row = rb0 + mf * 16 + i;
      float* o = out + (size_t)(b * L_ + row) * C_ + col0;
#pragma unroll
      for (int nf = 0; nf < 2; ++nf) o[nf * 16] = acc[mf][nf][i] + bia[nf];
    }
  }
}

extern "C" void kernel_launch(void* const* d_in, const int* in_sizes, int n_in,
                              void* d_out, int out_size, void* d_ws,
                              size_t ws_size, hipStream_t stream) {
  const float* x = (const float*)d_in[0];
  const int* segb = (const int*)d_in[1];      // [B][S][2] int32
  const float* w_dw = (const float*)d_in[2];  // [C][K]
  const float* b_dw = (const float*)d_in[3];  // [C]
  const float* w_pw = (const float*)d_in[4];  // [C_out][C_in]
  const float* b_pw = (const float*)d_in[5];  // [C]
  float* out = (float*)d_out;

  float* bias2 = (float*)d_ws;                   // 4 KB @ 0
  bf16* pkB = (bf16*)((char*)d_ws + 4096);       // 512 KB @ 4K
  bf16* dwp = (bf16*)((char*)d_ws + (1 << 20));  // 32 MB @ 1M

  bias_kernel<<<C_, 256, 0, stream>>>(w_pw, b_dw, b_pw, bias2);
  packB_kernel<<<128, 256, 0, stream>>>(w_pw, pkB);
  conv_kernel<<<512, 256, 0, stream>>>(x, segb, w_dw, dwp);
  gemm_kernel<<<NB * L_ / 64, 1024, 0, stream>>>(dwp, pkB, bias2, out);
}

// Round 11
// 46.216 us; speedup vs baseline: 1.3649x; 1.3649x over previous
//
#include <hip/hip_runtime.h>
#include <hip/hip_bf16.h>
#include <climits>

typedef __bf16 bf16;
typedef __bf16 bf16x4 __attribute__((ext_vector_type(4)));
typedef __bf16 bf16x8 __attribute__((ext_vector_type(8)));
typedef float f32x4 __attribute__((ext_vector_type(4)));

#define NB 8
#define L_ 4096
#define C_ 512
#define KW 5
#define NS 8
#define BM 64

// plain barrier with compiler fences (no counter drain)
#define BARRIER_MEM                                                            \
  do {                                                                         \
    __builtin_amdgcn_sched_barrier(0);                                         \
    __builtin_amdgcn_s_barrier();                                              \
    __builtin_amdgcn_sched_barrier(0);                                         \
  } while (0)
// writer-side: flush ds_writes, then barrier
#define DSFLUSH_BARRIER                                                        \
  do {                                                                         \
    asm volatile("s_waitcnt lgkmcnt(0)" ::: "memory");                         \
    BARRIER_MEM;                                                               \
  } while (0)

// ---------------------------------------------------------------------------
// bias2[n] = b_pw[n] + sum_c b_dw[c]*w_pw[n][c]   (fp32-exact)
// ---------------------------------------------------------------------------
__global__ __launch_bounds__(256) void bias_kernel(
    const float* __restrict__ w_pw, const float* __restrict__ b_dw,
    const float* __restrict__ b_pw, float* __restrict__ bias2) {
  const int n = blockIdx.x;
  const int t = threadIdx.x;
  float2 v = *(const float2*)(w_pw + n * C_ + 2 * t);
  float2 bb = *(const float2*)(b_dw + 2 * t);
  float s = v.x * bb.x + v.y * bb.y;
#pragma unroll
  for (int off = 32; off; off >>= 1) s += __shfl_down(s, off, 64);
  __shared__ float part[4];
  if ((t & 63) == 0) part[t >> 6] = s;
  __syncthreads();
  if (t == 0) bias2[n] = b_pw[n] + part[0] + part[1] + part[2] + part[3];
}

// ---------------------------------------------------------------------------
// pack: w_pw fp32 -> bf16 in MFMA B-fragment order for the 8-wave layout.
// gid = ((kk*8 + wn)*4 + nf)*64 + lane holds 8 bf16 (16B):
//   col n = wn*64 + nf*16 + (lane&15), ch c = kk*32 + (lane>>4)*8 .. +8
// ---------------------------------------------------------------------------
__global__ __launch_bounds__(256) void pack_kernel(const float* __restrict__ w_pw,
                                                   bf16* __restrict__ pk) {
  const int gid = blockIdx.x * 256 + threadIdx.x;  // 0..32767
  const int lane = gid & 63;
  const int nf = (gid >> 6) & 3;
  const int wnn = (gid >> 8) & 7;
  const int kk = gid >> 11;
  const int n = wnn * 64 + nf * 16 + (lane & 15);
  const int c = kk * 32 + (lane >> 4) * 8;
  const float* s = w_pw + n * C_ + c;
  float4 a = *(const float4*)s;
  float4 b4 = *(const float4*)(s + 4);
  bf16x8 h;
  h[0] = (bf16)a.x; h[1] = (bf16)a.y; h[2] = (bf16)a.z; h[3] = (bf16)a.w;
  h[4] = (bf16)b4.x; h[5] = (bf16)b4.y; h[6] = (bf16)b4.z; h[7] = (bf16)b4.w;
  *(bf16x8*)(pk + (size_t)gid * 8) = h;
}

// ---------------------------------------------------------------------------
// fused, producer/consumer wave-specialized, persistent per CU:
//  256 blocks x 1024 thr (16 waves). Block owns 128 consecutive rows
//  = 2 tiles of 64. As double-buffered (2 x 64 KB).
//  waves 8-15 (producers): rolling-window segment-causal conv
//      tile0 -> As[0]; BAR; tile1 -> As[1]; BAR; exit.
//  waves 0-7 (consumers): setup+prefetch; BAR; gemm(As[0])+write;
//      BAR; gemm(As[1])+write.
//  => gemm(tile0) overlaps conv(tile1) on every CU. 2 barriers/wave.
// ---------------------------------------------------------------------------
__global__ __launch_bounds__(1024, 4) void fused_kernel(
    const float* __restrict__ x, const int* __restrict__ segb,
    const float* __restrict__ w_dw, const bf16* __restrict__ pkB,
    const float* __restrict__ bias2, float* __restrict__ out) {
  __shared__ __align__(16) bf16 As[2][BM * C_];  // 128 KB

  const int t = threadIdx.x;
  const int lane = t & 63;
  const int wid = t >> 6;
  const int b = blockIdx.x >> 5;            // batch row
  const int base = (blockIdx.x & 31) << 7;  // 128-row span

  const f32x4 z4 = (f32x4){0.f, 0.f, 0.f, 0.f};

  if (wid >= 8) {
    // ================= producers: conv =================
    const int t2 = t - 512;        // 0..511
    const int q = t2 & 127;        // channel quad
    const int r0 = (t2 >> 7) << 4; // row strip 0/16/32/48

    float4 raw[5];
#pragma unroll
    for (int i = 0; i < 5; ++i)
      raw[i] = *(const float4*)(w_dw + q * 20 + i * 4);
    f32x4 wt[5];
#pragma unroll
    for (int m = 0; m < 5; ++m)
#pragma unroll
      for (int i = 0; i < 4; ++i) {
        const int f = i * 5 + m;
        wt[m][i] = ((const float*)&raw[f >> 2])[f & 3];
      }

    const int* sb = segb + b * NS * 2;
    int stv[NS];
#pragma unroll
    for (int s = 0; s < NS; ++s) stv[s] = sb[2 * s];
    auto nxt = [&](int l) {
      int nn = INT_MAX;
#pragma unroll
      for (int s = 0; s < NS; ++s)
        nn = (stv[s] > l && stv[s] < nn) ? stv[s] : nn;
      return nn;
    };

#pragma unroll 1
    for (int tile = 0; tile < 2; ++tile) {
      const int l0 = base + (tile << 6);
      bf16* Ab = (bf16*)As[tile];
      int ns = nxt(l0 + r0 - 4);
      const float* gxb = x + (size_t)(b * L_ + l0 + r0) * C_ + q * 4;

      f32x4 w0 = z4, w1 = z4, w2 = z4, w3 = z4;
#pragma unroll
      for (int i = 0; i < 4; ++i) {
        const int l = l0 + r0 - 4 + i;
        f32x4 nv = z4;
        if (l >= 0) nv = *(const f32x4*)(gxb + (ptrdiff_t)(i - 4) * C_);
        if (l == ns) { w0 = z4; w1 = z4; w2 = z4; w3 = z4; ns = nxt(l); }
        w0 = w1; w1 = w2; w2 = w3; w3 = nv;
      }

      auto dorow = [&](int l, f32x4& A, f32x4& B4, f32x4& Cc, f32x4& D,
                       const f32x4& E, int rloc) {
        if (l == ns) { A = z4; B4 = z4; Cc = z4; D = z4; ns = nxt(l); }
        f32x4 r;
#pragma unroll
        for (int i = 0; i < 4; ++i) {
          float a = A[i] * wt[0][i];
          a = fmaf(B4[i], wt[1][i], a);
          a = fmaf(Cc[i], wt[2][i], a);
          a = fmaf(D[i], wt[3][i], a);
          a = fmaf(E[i], wt[4][i], a);
          r[i] = a;
        }
        bf16x4 h;
#pragma unroll
        for (int i = 0; i < 4; ++i) h[i] = (bf16)r[i];
        const int u = q ^ ((rloc & 7) << 1);  // quad-unit XOR swizzle
        *(bf16x4*)&Ab[rloc * 512 + u * 4] = h;
      };

#pragma unroll
      for (int g = 0; g < 4; ++g) {
        const int lb = l0 + r0 + g * 4;
        f32x4 n0 = *(const f32x4*)(gxb + (ptrdiff_t)(g * 4 + 0) * C_);
        f32x4 n1 = *(const f32x4*)(gxb + (ptrdiff_t)(g * 4 + 1) * C_);
        f32x4 n2 = *(const f32x4*)(gxb + (ptrdiff_t)(g * 4 + 2) * C_);
        f32x4 n3 = *(const f32x4*)(gxb + (ptrdiff_t)(g * 4 + 3) * C_);
        dorow(lb + 0, w0, w1, w2, w3, n0, r0 + g * 4 + 0);
        dorow(lb + 1, w1, w2, w3, n0, n1, r0 + g * 4 + 1);
        dorow(lb + 2, w2, w3, n0, n1, n2, r0 + g * 4 + 2);
        dorow(lb + 3, w3, n0, n1, n2, n3, r0 + g * 4 + 3);
        w0 = n0; w1 = n1; w2 = n2; w3 = n3;
      }
      DSFLUSH_BARRIER;  // As[tile] published
    }
  } else {
    // ================= consumers: gemm =================
    const int wn = wid;        // 0..7, 64 cols each
    const int cg = lane >> 4;  // k-chunk group
    const int rx = lane & 7;

    int aRow[4];
#pragma unroll
    for (int mf = 0; mf < 4; ++mf) aRow[mf] = (mf * 16 + (lane & 15)) * 512;
    const bf16* pb = pkB + (size_t)wn * 2048 + lane * 8;

    const int col0 = wn * 64 + (lane & 15);
    float bia[4];
#pragma unroll
    for (int nf = 0; nf < 4; ++nf) bia[nf] = bias2[col0 + nf * 16];

    bf16x8 bbA[4], bbB[4], af[4];
#pragma unroll
    for (int nf = 0; nf < 4; ++nf)
      bbA[nf] = *(const bf16x8*)(pb + nf * 512);  // bb(0) in flight over BAR

#pragma unroll 1
    for (int tile = 0; tile < 2; ++tile) {
      BARRIER_MEM;  // As[tile] ready
      const bf16* Ab = (const bf16*)As[tile];

      f32x4 acc[4][4];
#pragma unroll
      for (int i = 0; i < 4; ++i)
#pragma unroll
        for (int j = 0; j < 4; ++j) acc[i][j] = z4;

#pragma unroll 1
      for (int kk = 0; kk < 16; kk += 2) {
        // even step: prefetch bb(kk+1), compute with bbA
#pragma unroll
        for (int nf = 0; nf < 4; ++nf)
          bbB[nf] = *(const bf16x8*)(pb + (kk + 1) * 16384 + nf * 512);
        const int ao = ((kk * 4 + cg) ^ rx) << 3;
#pragma unroll
        for (int mf = 0; mf < 4; ++mf)
          af[mf] = *(const bf16x8*)&Ab[aRow[mf] + ao];
        __builtin_amdgcn_s_setprio(1);
#pragma unroll
        for (int nf = 0; nf < 4; ++nf)
#pragma unroll
          for (int mf = 0; mf < 4; ++mf)
            acc[mf][nf] = __builtin_amdgcn_mfma_f32_16x16x32_bf16(
                af[mf], bbA[nf], acc[mf][nf], 0, 0, 0);
        __builtin_amdgcn_s_setprio(0);

        // odd step: prefetch bb(kk+2), compute with bbB
        if (kk + 2 < 16) {
#pragma unroll
          for (int nf = 0; nf < 4; ++nf)
            bbA[nf] = *(const bf16x8*)(pb + (kk + 2) * 16384 + nf * 512);
        }
        const int ao2 = (((kk + 1) * 4 + cg) ^ rx) << 3;
#pragma unroll
        for (int mf = 0; mf < 4; ++mf)
          af[mf] = *(const bf16x8*)&Ab[aRow[mf] + ao2];
        __builtin_amdgcn_s_setprio(1);
#pragma unroll
        for (int nf = 0; nf < 4; ++nf)
#pragma unroll
          for (int mf = 0; mf < 4; ++mf)
            acc[mf][nf] = __builtin_amdgcn_mfma_f32_16x16x32_bf16(
                af[mf], bbB[nf], acc[mf][nf], 0, 0, 0);
        __builtin_amdgcn_s_setprio(0);
      }

      // epilogue (stores drain async; no waits)
      const int l0 = base + (tile << 6);
      const int rb0 = l0 + (cg << 2);
#pragma unroll
      for (int mf = 0; mf < 4; ++mf) {
#pragma unroll
        for (int i = 0; i < 4; ++i) {
          const int row = rb0 + mf * 16 + i;
          float* o = out + (size_t)(b * L_ + row) * C_ + col0;
#pragma unroll
          for (int nf = 0; nf < 4; ++nf) o[nf * 16] = acc[mf][nf][i] + bia[nf];
        }
      }
      if (tile == 0) {  // re-arm bb(0) for tile1 (same weights, L2-hot)
#pragma unroll
        for (int nf = 0; nf < 4; ++nf)
          bbA[nf] = *(const bf16x8*)(pb + nf * 512);
      }
    }
  }
}

extern "C" void kernel_launch(void* const* d_in, const int* in_sizes, int n_in,
                              void* d_out, int out_size, void* d_ws,
                              size_t ws_size, hipStream_t stream) {
  const float* x = (const float*)d_in[0];
  const int* segb = (const int*)d_in[1];      // [B][S][2] int32
  const float* w_dw = (const float*)d_in[2];  // [C][K]
  const float* b_dw = (const float*)d_in[3];  // [C]
  const float* w_pw = (const float*)d_in[4];  // [C_out][C_in]
  const float* b_pw = (const float*)d_in[5];  // [C]
  float* out = (float*)d_out;

  float* bias2 = (float*)d_ws;             // 4 KB
  bf16* pkB = (bf16*)((char*)d_ws + 4096); // 512 KB packed B

  bias_kernel<<<C_, 256, 0, stream>>>(w_pw, b_dw, b_pw, bias2);
  pack_kernel<<<128, 256, 0, stream>>>(w_pw, pkB);
  fused_kernel<<<NB * L_ / 128, 1024, 0, stream>>>(x, segb, w_dw, pkB, bias2,
                                                   out);
}